// Round 1
// baseline (437.615 us; speedup 1.0000x reference)
//
#include <hip/hip_runtime.h>

#define K_CODES 1024
#define DIM 64
#define OUT_Q 8388608  // 32*64*64*64 quantized elements; loss at [OUT_Q]; indices at [OUT_Q+1..]

// ---- pass 1: ||e_k||^2 for each code ----
__global__ void vq_ee(const float* __restrict__ emb, float* __restrict__ ee) {
    int k = blockIdx.x * blockDim.x + threadIdx.x;
    if (k < K_CODES) {
        float s = 0.f;
        #pragma unroll
        for (int d = 0; d < DIM; ++d) {
            float v = emb[k * DIM + d];
            s = fmaf(v, v, s);
        }
        ee[k] = s;
    }
}

// ---- pass 2: argmin + gather + quantized write + loss partials ----
__global__ __launch_bounds__(256) void vq_main(
        const float* __restrict__ in, const float* __restrict__ emb,
        const float* __restrict__ ee, float* __restrict__ out,
        float* __restrict__ partials) {
    const int n = blockIdx.x * 256 + threadIdx.x;  // 0..131071 ; n = b*4096 + h*64 + w
    const int w = n & 63;
    const int h = (n >> 6) & 63;
    const int b = n >> 12;
    // in[b][c][h][w]: base for c=0; channel stride = 64*64 = 4096 elements
    const size_t base = ((size_t)b << 18) + ((size_t)h << 6) + (size_t)w;

    // load this position's 64-dim vector (coalesced: lanes = consecutive w)
    float x[DIM];
    #pragma unroll
    for (int d = 0; d < DIM; ++d) x[d] = in[base + ((size_t)d << 12)];

    // argmin_k ( ||e_k||^2 - 2 x.e_k )  -- ||x||^2 dropped (constant per n)
    float bestD = 3.4e38f;
    int bestK = 0;
    for (int k = 0; k < K_CODES; ++k) {
        const float* __restrict__ e = emb + k * DIM;  // wave-uniform -> scalar loads
        float a0 = 0.f, a1 = 0.f, a2 = 0.f, a3 = 0.f;
        #pragma unroll
        for (int d = 0; d < DIM; d += 4) {
            a0 = fmaf(x[d + 0], e[d + 0], a0);
            a1 = fmaf(x[d + 1], e[d + 1], a1);
            a2 = fmaf(x[d + 2], e[d + 2], a2);
            a3 = fmaf(x[d + 3], e[d + 3], a3);
        }
        float dist = ee[k] - 2.f * ((a0 + a1) + (a2 + a3));
        if (dist < bestD) { bestD = dist; bestK = k; }  // strict < : first-occurrence tie-break
    }

    // index output (stored as float; harness reads whole buffer as one dtype)
    out[OUT_Q + 1 + n] = (float)bestK;

    // gather chosen code, write quantized (straight-through == quantized), accumulate loss
    const float* __restrict__ eq = emb + bestK * DIM;  // per-lane gather, L2-hot (256 KB table)
    float errs = 0.f;
    #pragma unroll
    for (int d = 0; d < DIM; ++d) {
        float q = eq[d];
        float diff = q - x[d];
        errs = fmaf(diff, diff, errs);
        out[base + ((size_t)d << 12)] = q;  // coalesced stores (lanes = w)
    }

    // wave reduce (64 lanes) then block reduce 4 waves
    #pragma unroll
    for (int off = 32; off > 0; off >>= 1) errs += __shfl_xor(errs, off, 64);

    __shared__ float red[4];
    const int wave = threadIdx.x >> 6;
    const int lane = threadIdx.x & 63;
    if (lane == 0) red[wave] = errs;
    __syncthreads();
    if (threadIdx.x == 0) {
        partials[blockIdx.x] = (red[0] + red[1]) + (red[2] + red[3]);
    }
}

// ---- pass 3: deterministic final loss reduction ----
__global__ void vq_loss(const float* __restrict__ partials, float* __restrict__ out) {
    if (threadIdx.x == 0 && blockIdx.x == 0) {
        float s = 0.f;
        for (int i = 0; i < 512; ++i) s += partials[i];
        // loss = q_latent + 0.25*e_latent = 1.25 * mean((q - x)^2)
        out[OUT_Q] = s * (float)(1.25 / 8388608.0);
    }
}

extern "C" void kernel_launch(void* const* d_in, const int* in_sizes, int n_in,
                              void* d_out, int out_size, void* d_ws, size_t ws_size,
                              hipStream_t stream) {
    const float* in  = (const float*)d_in[0];   // [32,64,64,64] f32
    const float* emb = (const float*)d_in[1];   // [1024,64] f32
    float* out = (float*)d_out;
    float* ee = (float*)d_ws;              // 1024 floats
    float* partials = ee + K_CODES;        // 512 floats

    vq_ee<<<4, 256, 0, stream>>>(emb, ee);
    vq_main<<<512, 256, 0, stream>>>(in, emb, ee, out, partials);
    vq_loss<<<1, 64, 0, stream>>>(partials, out);
}

// Round 2
// 369.985 us; speedup vs baseline: 1.1828x; 1.1828x over previous
//
#include <hip/hip_runtime.h>

#define K_CODES 1024
#define DIM 64
#define OUT_Q 8388608  // 32*64*64*64 quantized elements; loss at [OUT_Q]; indices at [OUT_Q+1..]

typedef float v2 __attribute__((ext_vector_type(2)));

#if __has_builtin(__builtin_elementwise_fma)
#define FMA2(a, b, c) __builtin_elementwise_fma((a), (b), (c))
#else
static __device__ inline v2 FMA2(v2 a, v2 b, v2 c) {
    v2 r; r.x = fmaf(a.x, b.x, c.x); r.y = fmaf(a.y, b.y, c.y); return r;
}
#endif

// ---- pass 1: ||e_k||^2 for each code ----
__global__ void vq_ee(const float* __restrict__ emb, float* __restrict__ ee) {
    int k = blockIdx.x * blockDim.x + threadIdx.x;
    if (k < K_CODES) {
        float s = 0.f;
        #pragma unroll
        for (int d = 0; d < DIM; ++d) {
            float v = emb[k * DIM + d];
            s = fmaf(v, v, s);
        }
        ee[k] = s;
    }
}

// ---- pass 2: argmin + gather + quantized write + loss partials ----
__global__ __launch_bounds__(256) void vq_main(
        const float* __restrict__ in, const float* __restrict__ emb,
        const float* __restrict__ ee, float* __restrict__ out,
        float* __restrict__ partials) {
    const int n = blockIdx.x * 256 + threadIdx.x;  // n = b*4096 + h*64 + w
    const int w = n & 63;
    const int h = (n >> 6) & 63;
    const int b = n >> 12;
    // in[b][c][h][w]: channel stride = 4096 elements
    const size_t base = ((size_t)b << 18) + ((size_t)h << 6) + (size_t)w;

    // load this position's 64-dim vector into 32 float2 (coalesced: lanes = w)
    v2 x[32];
    #pragma unroll
    for (int d = 0; d < 32; ++d) {
        x[d].x = in[base + ((size_t)(2 * d + 0) << 12)];
        x[d].y = in[base + ((size_t)(2 * d + 1) << 12)];
    }
    // pin x in VGPRs: asm is now the producer, loads can't be rematerialized
    asm volatile("" : "+v"(x[0]), "+v"(x[1]), "+v"(x[2]), "+v"(x[3]),
                      "+v"(x[4]), "+v"(x[5]), "+v"(x[6]), "+v"(x[7]),
                      "+v"(x[8]), "+v"(x[9]), "+v"(x[10]), "+v"(x[11]),
                      "+v"(x[12]), "+v"(x[13]), "+v"(x[14]), "+v"(x[15]));
    asm volatile("" : "+v"(x[16]), "+v"(x[17]), "+v"(x[18]), "+v"(x[19]),
                      "+v"(x[20]), "+v"(x[21]), "+v"(x[22]), "+v"(x[23]),
                      "+v"(x[24]), "+v"(x[25]), "+v"(x[26]), "+v"(x[27]),
                      "+v"(x[28]), "+v"(x[29]), "+v"(x[30]), "+v"(x[31]));

    // argmin_k ( ||e_k||^2 - 2 x.e_k )  -- ||x||^2 dropped (constant per n)
    float bestD = 3.4e38f;
    int bestK = 0;
    for (int k = 0; k < K_CODES; ++k) {
        const v2* __restrict__ e = (const v2*)(emb + (size_t)k * DIM);  // wave-uniform -> s_load
        v2 a0 = {0.f, 0.f}, a1 = {0.f, 0.f}, a2 = {0.f, 0.f}, a3 = {0.f, 0.f};
        #pragma unroll
        for (int d = 0; d < 32; d += 4) {
            a0 = FMA2(x[d + 0], e[d + 0], a0);
            a1 = FMA2(x[d + 1], e[d + 1], a1);
            a2 = FMA2(x[d + 2], e[d + 2], a2);
            a3 = FMA2(x[d + 3], e[d + 3], a3);
        }
        v2 s = (a0 + a1) + (a2 + a3);
        float dist = ee[k] - 2.f * (s.x + s.y);
        if (dist < bestD) { bestD = dist; bestK = k; }  // strict < : first-occurrence tie-break
    }

    // index output (stored as float)
    out[OUT_Q + 1 + n] = (float)bestK;

    // gather chosen code, write quantized, accumulate loss
    const v2* __restrict__ eq = (const v2*)(emb + (size_t)bestK * DIM);  // per-lane gather, L2-hot
    v2 errs2 = {0.f, 0.f};
    #pragma unroll
    for (int d = 0; d < 32; ++d) {
        v2 q = eq[d];
        v2 diff = q - x[d];
        errs2 = FMA2(diff, diff, errs2);
        out[base + ((size_t)(2 * d + 0) << 12)] = q.x;  // coalesced stores (lanes = w)
        out[base + ((size_t)(2 * d + 1) << 12)] = q.y;
    }
    float errs = errs2.x + errs2.y;

    // wave reduce (64 lanes) then block reduce 4 waves
    #pragma unroll
    for (int off = 32; off > 0; off >>= 1) errs += __shfl_xor(errs, off, 64);

    __shared__ float red[4];
    const int wave = threadIdx.x >> 6;
    const int lane = threadIdx.x & 63;
    if (lane == 0) red[wave] = errs;
    __syncthreads();
    if (threadIdx.x == 0) {
        partials[blockIdx.x] = (red[0] + red[1]) + (red[2] + red[3]);
    }
}

// ---- pass 3: deterministic final loss reduction ----
__global__ void vq_loss(const float* __restrict__ partials, float* __restrict__ out) {
    if (threadIdx.x == 0 && blockIdx.x == 0) {
        float s = 0.f;
        for (int i = 0; i < 512; ++i) s += partials[i];
        // loss = q_latent + 0.25*e_latent = 1.25 * mean((q - x)^2)
        out[OUT_Q] = s * (float)(1.25 / 8388608.0);
    }
}

extern "C" void kernel_launch(void* const* d_in, const int* in_sizes, int n_in,
                              void* d_out, int out_size, void* d_ws, size_t ws_size,
                              hipStream_t stream) {
    const float* in  = (const float*)d_in[0];   // [32,64,64,64] f32
    const float* emb = (const float*)d_in[1];   // [1024,64] f32
    float* out = (float*)d_out;
    float* ee = (float*)d_ws;              // 1024 floats
    float* partials = ee + K_CODES;        // 512 floats

    vq_ee<<<4, 256, 0, stream>>>(emb, ee);
    vq_main<<<512, 256, 0, stream>>>(in, emb, ee, out, partials);
    vq_loss<<<1, 64, 0, stream>>>(partials, out);
}

// Round 3
// 231.338 us; speedup vs baseline: 1.8917x; 1.5993x over previous
//
#include <hip/hip_runtime.h>

#define K_CODES 1024
#define DIM 64
#define OUT_Q 8388608  // 32*64*64*64 quantized elems; loss at [OUT_Q]; indices at [OUT_Q+1..]
#define NPOS 131072
#define SPLIT 4

typedef float v2 __attribute__((ext_vector_type(2)));

#if __has_builtin(__builtin_elementwise_fma)
#define FMA2(a, b, c) __builtin_elementwise_fma((a), (b), (c))
#else
static __device__ inline v2 FMA2(v2 a, v2 b, v2 c) {
    v2 r; r.x = fmaf(a.x, b.x, c.x); r.y = fmaf(a.y, b.y, c.y); return r;
}
#endif

// ---- pass 1: ||e_k||^2 for each code ----
__global__ void vq_ee(const float* __restrict__ emb, float* __restrict__ ee) {
    int k = blockIdx.x * blockDim.x + threadIdx.x;
    if (k < K_CODES) {
        float s = 0.f;
        #pragma unroll
        for (int d = 0; d < DIM; ++d) {
            float v = emb[k * DIM + d];
            s = fmaf(v, v, s);
        }
        ee[k] = s;
    }
}

// ---- pass 2: partial argmin over a code range (K-split for occupancy) ----
__global__ __launch_bounds__(256, 4) void vq_dist(
        const float* __restrict__ in, const float* __restrict__ emb,
        const float* __restrict__ ee, float* __restrict__ dist,
        int* __restrict__ idx, int nPosBlocks) {
    const int pg = blockIdx.x % nPosBlocks;
    const int sp = blockIdx.x / nPosBlocks;          // split id (0..SPLIT-1)
    const int n = pg * 256 + threadIdx.x;            // n = b*4096 + h*64 + w
    const int w = n & 63;
    const int h = (n >> 6) & 63;
    const int b = n >> 12;
    const size_t base = ((size_t)b << 18) + ((size_t)h << 6) + (size_t)w;  // channel stride 4096

    // load this position's 64-dim vector into 32 float2 (coalesced: lanes = w)
    v2 x[32];
    #pragma unroll
    for (int d = 0; d < 32; ++d) {
        x[d].x = in[base + ((size_t)(2 * d + 0) << 12)];
        x[d].y = in[base + ((size_t)(2 * d + 1) << 12)];
    }
    asm volatile("" : "+v"(x[0]), "+v"(x[1]), "+v"(x[2]), "+v"(x[3]),
                      "+v"(x[4]), "+v"(x[5]), "+v"(x[6]), "+v"(x[7]),
                      "+v"(x[8]), "+v"(x[9]), "+v"(x[10]), "+v"(x[11]),
                      "+v"(x[12]), "+v"(x[13]), "+v"(x[14]), "+v"(x[15]));
    asm volatile("" : "+v"(x[16]), "+v"(x[17]), "+v"(x[18]), "+v"(x[19]),
                      "+v"(x[20]), "+v"(x[21]), "+v"(x[22]), "+v"(x[23]),
                      "+v"(x[24]), "+v"(x[25]), "+v"(x[26]), "+v"(x[27]),
                      "+v"(x[28]), "+v"(x[29]), "+v"(x[30]), "+v"(x[31]));

    const int kbase = sp * (K_CODES / SPLIT);
    const int kend = kbase + (K_CODES / SPLIT);

    float bestD = 3.4e38f;
    int bestK = kbase;
    #pragma unroll 2
    for (int k = kbase; k < kend; ++k) {
        const v2* __restrict__ e = (const v2*)(emb + (size_t)k * DIM);  // wave-uniform -> s_load
        v2 a0 = {0.f, 0.f}, a1 = {0.f, 0.f}, a2 = {0.f, 0.f}, a3 = {0.f, 0.f};
        #pragma unroll
        for (int d = 0; d < 32; d += 4) {
            a0 = FMA2(x[d + 0], e[d + 0], a0);
            a1 = FMA2(x[d + 1], e[d + 1], a1);
            a2 = FMA2(x[d + 2], e[d + 2], a2);
            a3 = FMA2(x[d + 3], e[d + 3], a3);
        }
        v2 s2 = (a0 + a1) + (a2 + a3);
        float dk = fmaf(-2.f, s2.x + s2.y, ee[k]);   // == ee - 2*dot (contracted, as R2)
        if (dk < bestD) { bestD = dk; bestK = k; }   // strict < : first occurrence
    }
    dist[(size_t)sp * NPOS + n] = bestD;
    idx[(size_t)sp * NPOS + n] = bestK;
}

// ---- pass 3: combine splits, gather, quantized write, loss partials ----
__global__ __launch_bounds__(256) void vq_combine(
        const float* __restrict__ in, const float* __restrict__ emb,
        const float* __restrict__ dist, const int* __restrict__ idx,
        float* __restrict__ out, float* __restrict__ partials, int nsplit) {
    const int n = blockIdx.x * 256 + threadIdx.x;
    const int w = n & 63;
    const int h = (n >> 6) & 63;
    const int b = n >> 12;
    const size_t base = ((size_t)b << 18) + ((size_t)h << 6) + (size_t)w;

    // combine in split order: preserves global first-occurrence tie-break
    float bestD = dist[n];
    int bestK = idx[n];
    for (int s = 1; s < nsplit; ++s) {
        float d = dist[(size_t)s * NPOS + n];
        int kk = idx[(size_t)s * NPOS + n];
        if (d < bestD) { bestD = d; bestK = kk; }
    }
    out[OUT_Q + 1 + n] = (float)bestK;

    const v2* __restrict__ eq = (const v2*)(emb + (size_t)bestK * DIM);  // L2-hot gather
    v2 errs2 = {0.f, 0.f};
    #pragma unroll
    for (int d = 0; d < 32; ++d) {
        v2 q = eq[d];
        v2 xv;
        xv.x = in[base + ((size_t)(2 * d + 0) << 12)];
        xv.y = in[base + ((size_t)(2 * d + 1) << 12)];
        v2 diff = q - xv;
        errs2 = FMA2(diff, diff, errs2);
        out[base + ((size_t)(2 * d + 0) << 12)] = q.x;  // coalesced stores
        out[base + ((size_t)(2 * d + 1) << 12)] = q.y;
    }
    float errs = errs2.x + errs2.y;

    #pragma unroll
    for (int off = 32; off > 0; off >>= 1) errs += __shfl_xor(errs, off, 64);

    __shared__ float red[4];
    const int wave = threadIdx.x >> 6;
    const int lane = threadIdx.x & 63;
    if (lane == 0) red[wave] = errs;
    __syncthreads();
    if (threadIdx.x == 0) {
        partials[blockIdx.x] = (red[0] + red[1]) + (red[2] + red[3]);
    }
}

// ---- pass 4: deterministic final loss reduction ----
__global__ void vq_loss(const float* __restrict__ partials, float* __restrict__ out) {
    if (threadIdx.x == 0 && blockIdx.x == 0) {
        float s = 0.f;
        for (int i = 0; i < 512; ++i) s += partials[i];
        out[OUT_Q] = s * (float)(1.25 / 8388608.0);  // q_loss + 0.25*e_loss
    }
}

extern "C" void kernel_launch(void* const* d_in, const int* in_sizes, int n_in,
                              void* d_out, int out_size, void* d_ws, size_t ws_size,
                              hipStream_t stream) {
    const float* in  = (const float*)d_in[0];   // [32,64,64,64] f32
    const float* emb = (const float*)d_in[1];   // [1024,64] f32
    float* out = (float*)d_out;

    // ws layout: ee[1024] | dist[SPLIT][NPOS] | idx[SPLIT][NPOS] | partials[512]
    float* ee = (float*)d_ws;
    float* dist = ee + K_CODES;
    const size_t need_full = (size_t)(K_CODES + 2 * SPLIT * NPOS + 512) * 4;
    const int nsplit = (ws_size >= need_full) ? SPLIT : 1;

    int* idx = (int*)(dist + (size_t)nsplit * NPOS);
    float* partials = (float*)(idx + (size_t)nsplit * NPOS);

    vq_ee<<<4, 256, 0, stream>>>(emb, ee);
    vq_dist<<<512 * nsplit, 256, 0, stream>>>(in, emb, ee, dist, idx, 512);
    vq_combine<<<512, 256, 0, stream>>>(in, emb, dist, idx, out, partials, nsplit);
    vq_loss<<<1, 64, 0, stream>>>(partials, out);
}